// Round 5
// baseline (60.372 us; speedup 1.0000x reference)
//
#include <hip/hip_runtime.h>
#include <hip/hip_bf16.h>

// Problem constants (fixed by setup_inputs)
#define BB   4
#define CF   256
#define CC   64
#define CP   80
#define HH   128   // hi-res
#define WW   128
#define KK   25
#define NPIX 16384 // 128*128

typedef __attribute__((ext_vector_type(8))) short short8v;
typedef __attribute__((ext_vector_type(4))) short short4v;
typedef __attribute__((ext_vector_type(4))) float f32x4;
typedef __attribute__((ext_vector_type(2))) float f32x2;

static __device__ __forceinline__ short f2bf(float f) {
  __hip_bfloat16 h = __float2bfloat16(f);
  return *reinterpret_cast<short*>(&h);
}

// =================== K1: compress (1x1 conv) via bf16 MFMA ==============
// guide[b][y][x][c] bf16 = sum_c' feat[b][c'][y][x] * wc[c][c'] + bc[c]
// grid 1024 = 4 b x 128 y x 2 x-halves (64 px). block 256 (4 waves).
__global__ __launch_bounds__(256) void k_compress(
    const float* __restrict__ feat, const float* __restrict__ wc,
    const float* __restrict__ bc, const float* __restrict__ we,
    short* __restrict__ guide, short* __restrict__ web) {
  __shared__ short Al[32 * 520];  // [(cblk*4+lh)][o(64)*8], pad 512->520
  __shared__ short Bl[64 * 72];   // [px][c 0..63], stride 72
  const int tid = threadIdx.x;
  const int bx = blockIdx.x;
  const int b = bx >> 8;
  const int y = (bx >> 1) & 127;
  const int x0 = (bx & 1) << 6;

  // distributed web prestage: web[tap][kk pad32][c], zero for kk>=25
  {
    int j = bx * 256 + tid;
    if (j < 9 * 32 * 64) {
      int tap = j >> 11, kk = (j >> 6) & 31, c = j & 63;
      float v = (kk < KK) ? we[(kk * 64 + c) * 9 + tap] : 0.f;
      web[j] = f2bf(v);
    }
  }

  // convert wc (64x256 f32) -> Al in fragment order
#pragma unroll
  for (int t = 0; t < 8; ++t) {
    int idx = tid + t * 256;  // 0..2047
    int o = idx >> 5, c8 = idx & 31;
    const f32x4* src = (const f32x4*)(wc + o * CF + c8 * 8);
    f32x4 v0 = src[0], v1 = src[1];
    short8v h;
    h[0] = f2bf(v0.x); h[1] = f2bf(v0.y); h[2] = f2bf(v0.z); h[3] = f2bf(v0.w);
    h[4] = f2bf(v1.x); h[5] = f2bf(v1.y); h[6] = f2bf(v1.z); h[7] = f2bf(v1.w);
    int cblk = c8 >> 2, lh4 = c8 & 3;
    *(short8v*)(Al + (cblk * 4 + lh4) * 520 + o * 8) = h;
  }

  const int wave = tid >> 6, l = tid & 63;
  const int l15 = l & 15, lh = l >> 4;
  const int px_s = tid & 63;          // staging pixel
  const int c_s = (tid >> 6) << 4;    // staging channel offset (16/wave)
  const float* fb = feat + (size_t)b * CF * NPIX + y * WW + x0;

  f32x4 acc[4];
#pragma unroll
  for (int m = 0; m < 4; ++m) acc[m] = (f32x4){0.f, 0.f, 0.f, 0.f};

  for (int c0 = 0; c0 < CF; c0 += 64) {
    if (c0) __syncthreads();
    float v[16];
#pragma unroll
    for (int i = 0; i < 16; ++i)
      v[i] = fb[(size_t)(c0 + c_s + i) * NPIX + px_s];
    short8v h0, h1;
#pragma unroll
    for (int e = 0; e < 8; ++e) { h0[e] = f2bf(v[e]); h1[e] = f2bf(v[8 + e]); }
    *(short8v*)(Bl + px_s * 72 + c_s) = h0;
    *(short8v*)(Bl + px_s * 72 + c_s + 8) = h1;
    __syncthreads();  // Bl (and, first pass, Al) visible
#pragma unroll
    for (int ks = 0; ks < 64; ks += 32) {
      const int cblk = (c0 + ks) >> 5;
      short8v bfr = *(const short8v*)(Bl + (wave * 16 + l15) * 72 + ks + lh * 8);
#pragma unroll
      for (int m = 0; m < 4; ++m) {
        short8v a = *(const short8v*)(Al + (cblk * 4 + lh) * 520 +
                                      (m * 16 + l15) * 8);
        acc[m] = __builtin_amdgcn_mfma_f32_16x16x32_bf16(a, bfr, acc[m], 0, 0, 0);
      }
    }
  }

  // epilogue: +bias, cvt bf16, store [b][y][x][c]
  const int px = wave * 16 + l15;
  short* gb = guide + ((size_t)((b * HH + y) * WW + x0 + px)) * CC;
#pragma unroll
  for (int m = 0; m < 4; ++m) {
    short4v o;
#pragma unroll
    for (int r = 0; r < 4; ++r) {
      int c = m * 16 + lh * 4 + r;
      o[r] = f2bf(acc[m][r] + bc[c]);
    }
    *(short4v*)(gb + m * 16 + lh * 4) = o;
  }
}

// ======= K2: conv3x3 + bias + softmax + CARAFE, fused per 8x8 tile ======
// Phase 1: conv via MFMA (M=32 kk, K=64 c, N=64 px), softmax -> Ml (f32 LDS).
// Phase 2: carafe. Thread = horizontal px pair (shares 5x5 patch) x 10 ch.
// Pl channel-innermost [cell(64)][c pad82] -> f32x2 loads, m[2][25] in regs.
__global__ __launch_bounds__(256) void k_conv_carafe(
    const short* __restrict__ guide, const short* __restrict__ web,
    const float* __restrict__ be, const float* __restrict__ pred,
    float* __restrict__ out) {
  __shared__ char smem[20992 + 7168];
  short* Gl = (short*)smem;             // [10][10][72] = 14400 B
  float* Pl = (float*)smem;             // [64][82]     = 20992 B (reuses Gl)
  float* Ml = (float*)(smem + 20992);   // [64][28]     = 7168 B
  const int tid = threadIdx.x;
  const int bx = blockIdx.x;
  const int b = bx >> 8;
  const int t = bx & 255;
  const int y0 = (t >> 4) << 3, x0 = (t & 15) << 3;
  const int wave = tid >> 6, l = tid & 63;
  const int l15 = l & 15, lh = l >> 4;

  // ---- stage guide halo tile (zero-pad) ----
  for (int idx = tid; idx < 10 * 10 * 8; idx += 256) {
    int yp = idx / 80;
    int rem = idx - yp * 80;
    int xp = rem >> 3, cq = (rem & 7) << 3;
    int gy = y0 - 1 + yp, gx = x0 - 1 + xp;
    short8v v = {0, 0, 0, 0, 0, 0, 0, 0};
    if (gy >= 0 && gy < HH && gx >= 0 && gx < WW)
      v = *(const short8v*)(guide + ((size_t)((b * HH + gy) * WW + gx)) * CC + cq);
    *(short8v*)(Gl + (yp * 10 + xp) * 72 + cq) = v;
  }
  __syncthreads();

  // ---- conv MFMA: px = wave*16 + l15 -> (row, col) in 8x8 tile ----
  const int r_ = wave * 2 + (l15 >> 3);  // tile row 0..7
  const int cx = l15 & 7;                // tile col 0..7
  f32x4 acc0 = {0.f, 0.f, 0.f, 0.f}, acc1 = {0.f, 0.f, 0.f, 0.f};
#pragma unroll
  for (int tap = 0; tap < 9; ++tap) {
    const int dy = tap / 3, dx = tap - dy * 3;
#pragma unroll
    for (int ks = 0; ks < 64; ks += 32) {
      short8v a0 = *(const short8v*)(web + (tap * 32 + l15) * 64 + ks + lh * 8);
      short8v a1 =
          *(const short8v*)(web + (tap * 32 + 16 + l15) * 64 + ks + lh * 8);
      short8v bf = *(const short8v*)(Gl + ((r_ + dy) * 10 + cx + dx) * 72 +
                                     ks + lh * 8);
      acc0 = __builtin_amdgcn_mfma_f32_16x16x32_bf16(a0, bf, acc0, 0, 0, 0);
      acc1 = __builtin_amdgcn_mfma_f32_16x16x32_bf16(a1, bf, acc1, 0, 0, 0);
    }
  }

  // ---- bias + softmax over kk (25 vals in 4 lanes: xor 16,32) -> Ml ----
  {
    float sv[8];
#pragma unroll
    for (int r = 0; r < 4; ++r) {
      int kk0 = lh * 4 + r;            // 0..15, always < 25
      sv[r] = acc0[r] + be[kk0];
      int kk1 = 16 + lh * 4 + r;       // 16..31
      sv[4 + r] = (kk1 < KK) ? (acc1[r] + be[kk1]) : -1e30f;
    }
    float mx = sv[0];
#pragma unroll
    for (int i = 1; i < 8; ++i) mx = fmaxf(mx, sv[i]);
    mx = fmaxf(mx, __shfl_xor(mx, 16));
    mx = fmaxf(mx, __shfl_xor(mx, 32));
    float s = 0.f;
#pragma unroll
    for (int i = 0; i < 8; ++i) {
      sv[i] = __expf(sv[i] - mx);
      s += sv[i];
    }
    s += __shfl_xor(s, 16);
    s += __shfl_xor(s, 32);
    float inv = 1.f / s;
    int pxm = wave * 16 + l15;  // == r_*8 + cx
#pragma unroll
    for (int r = 0; r < 4; ++r) {
      Ml[pxm * 28 + lh * 4 + r] = sv[r] * inv;
      int kk1 = 16 + lh * 4 + r;
      if (kk1 < KK) Ml[pxm * 28 + kk1] = sv[4 + r] * inv;
    }
  }
  __syncthreads();  // Ml complete; Gl no longer needed

  // ---- stage Pl: [cell 64][c pad 82], reflect-padded lo tile ----
  const int ylo = (y0 >> 1) - 2, xlo = (x0 >> 1) - 2;
#pragma unroll
  for (int it = 0; it < 20; ++it) {
    int idx = it * 256 + tid;          // 0..5119
    int c = idx >> 6;                  // 0..79
    int cell = idx & 63;
    int r = cell >> 3, cl = cell & 7;
    int ry = ylo + r;
    ry = ry < 0 ? -ry : (ry > 63 ? 126 - ry : ry);
    int rx = xlo + cl;
    rx = rx < 0 ? -rx : (rx > 63 ? 126 - rx : rx);
    Pl[cell * 82 + c] = pred[(((size_t)b * CP + c) << 12) + (ry << 6) + rx];
  }

  // ---- pair masks -> registers (reads Ml; disjoint from Pl writes) ----
  const int g = tid >> 5;              // 0..7 -> 10-channel group
  const int pr = tid & 31;             // pair id: pry(0..7) x prx(0..3)
  const int pry = pr >> 2, prx = pr & 3;
  float m[2][KK];
#pragma unroll
  for (int dx = 0; dx < 2; ++dx) {
    int pxl = pry * 8 + prx * 2 + dx;
    const f32x4* mp = (const f32x4*)(Ml + pxl * 28);
#pragma unroll
    for (int v4 = 0; v4 < 7; ++v4) {
      f32x4 mv = mp[v4];
#pragma unroll
      for (int e = 0; e < 4; ++e) {
        int kk = v4 * 4 + e;
        if (kk < KK) m[dx][kk] = mv[e];
      }
    }
  }
  __syncthreads();  // Pl ready

  // ---- carafe: 5 ch-pairs x 2 px per thread, f32x2 patch loads ----
  const int Y = y0 + pry, X = x0 + prx * 2;
  const float* Pbase = Pl + ((pry >> 1) * 8 + prx) * 82 + g * 10;
#pragma unroll
  for (int cp = 0; cp < 5; ++cp) {
    f32x2 a0 = {0.f, 0.f}, a1 = {0.f, 0.f};
#pragma unroll
    for (int i = 0; i < 5; ++i)
#pragma unroll
      for (int j = 0; j < 5; ++j) {
        f32x2 p2 = *(const f32x2*)(Pbase + (i * 8 + j) * 82 + cp * 2);
        float m0 = m[0][i * 5 + j], m1 = m[1][i * 5 + j];
        a0.x += p2.x * m0;
        a0.y += p2.x * m1;
        a1.x += p2.y * m0;
        a1.y += p2.y * m1;
      }
    float* ob = out + (((size_t)(b * CP + g * 10 + cp * 2)) << 14) + Y * WW + X;
    *(f32x2*)ob = a0;
    *(f32x2*)(ob + NPIX) = a1;
  }
}

extern "C" void kernel_launch(void* const* d_in, const int* in_sizes, int n_in,
                              void* d_out, int out_size, void* d_ws,
                              size_t ws_size, hipStream_t stream) {
  (void)in_sizes; (void)n_in; (void)out_size; (void)ws_size;
  const float* pred = (const float*)d_in[0];  // (4,80,64,64)
  const float* feat = (const float*)d_in[1];  // (4,256,128,128)
  const float* wc   = (const float*)d_in[2];  // (64,256)
  const float* bc   = (const float*)d_in[3];  // (64)
  const float* we   = (const float*)d_in[4];  // (25,64,3,3)
  const float* be   = (const float*)d_in[5];  // (25)
  float* out = (float*)d_out;                 // (4,80,128,128)

  char* ws = (char*)d_ws;
  short* guide = (short*)ws;             // 8,388,608 B (bf16, [b][y][x][c])
  short* web   = (short*)(ws + 8388608); // 36,864 B (bf16 [tap][kk32][c])

  hipLaunchKernelGGL(k_compress, dim3(1024), dim3(256), 0, stream,
                     feat, wc, bc, we, guide, web);
  hipLaunchKernelGGL(k_conv_carafe, dim3(1024), dim3(256), 0, stream,
                     guide, web, be, pred, out);
}

// Round 6
// 56.904 us; speedup vs baseline: 1.0609x; 1.0609x over previous
//
#include <hip/hip_runtime.h>
#include <hip/hip_bf16.h>

// Problem constants (fixed by setup_inputs)
#define BB   4
#define CF   256
#define CC   64
#define CP   80
#define HH   128   // hi-res
#define WW   128
#define KK   25
#define NPIX 16384 // 128*128

typedef __attribute__((ext_vector_type(8))) short short8v;
typedef __attribute__((ext_vector_type(4))) short short4v;
typedef __attribute__((ext_vector_type(4))) float f32x4;
typedef __attribute__((ext_vector_type(2))) float f32x2;

static __device__ __forceinline__ short f2bf(float f) {
  __hip_bfloat16 h = __float2bfloat16(f);
  return *reinterpret_cast<short*>(&h);
}

// =================== K1: compress (1x1 conv) via bf16 MFMA ==============
// guide[b][y][x][c] bf16 = sum_c' feat[b][c'][y][x] * wc[c][c'] + bc[c]
// grid 1024 = 4 b x 128 y x 2 x-halves (64 px). block 256 (4 waves).
__global__ __launch_bounds__(256) void k_compress(
    const float* __restrict__ feat, const float* __restrict__ wc,
    const float* __restrict__ bc, const float* __restrict__ we,
    short* __restrict__ guide, short* __restrict__ web) {
  __shared__ short Al[32 * 520];  // [(cblk*4+lh)][o(64)*8], pad 512->520
  __shared__ short Bl[64 * 72];   // [px][c 0..63], stride 72
  const int tid = threadIdx.x;
  const int bx = blockIdx.x;
  const int b = bx >> 8;
  const int y = (bx >> 1) & 127;
  const int x0 = (bx & 1) << 6;

  // distributed web prestage: web[tap][kk pad32][c], zero for kk>=25
  {
    int j = bx * 256 + tid;
    if (j < 9 * 32 * 64) {
      int tap = j >> 11, kk = (j >> 6) & 31, c = j & 63;
      float v = (kk < KK) ? we[(kk * 64 + c) * 9 + tap] : 0.f;
      web[j] = f2bf(v);
    }
  }

  // convert wc (64x256 f32) -> Al in fragment order
#pragma unroll
  for (int t = 0; t < 8; ++t) {
    int idx = tid + t * 256;  // 0..2047
    int o = idx >> 5, c8 = idx & 31;
    const f32x4* src = (const f32x4*)(wc + o * CF + c8 * 8);
    f32x4 v0 = src[0], v1 = src[1];
    short8v h;
    h[0] = f2bf(v0.x); h[1] = f2bf(v0.y); h[2] = f2bf(v0.z); h[3] = f2bf(v0.w);
    h[4] = f2bf(v1.x); h[5] = f2bf(v1.y); h[6] = f2bf(v1.z); h[7] = f2bf(v1.w);
    int cblk = c8 >> 2, lh4 = c8 & 3;
    *(short8v*)(Al + (cblk * 4 + lh4) * 520 + o * 8) = h;
  }

  const int wave = tid >> 6, l = tid & 63;
  const int l15 = l & 15, lh = l >> 4;
  const int px_s = tid & 63;          // staging pixel
  const int c_s = (tid >> 6) << 4;    // staging channel offset (16/wave)
  const float* fb = feat + (size_t)b * CF * NPIX + y * WW + x0;

  f32x4 acc[4];
#pragma unroll
  for (int m = 0; m < 4; ++m) acc[m] = (f32x4){0.f, 0.f, 0.f, 0.f};

  for (int c0 = 0; c0 < CF; c0 += 64) {
    if (c0) __syncthreads();
    float v[16];
#pragma unroll
    for (int i = 0; i < 16; ++i)
      v[i] = fb[(size_t)(c0 + c_s + i) * NPIX + px_s];
    short8v h0, h1;
#pragma unroll
    for (int e = 0; e < 8; ++e) { h0[e] = f2bf(v[e]); h1[e] = f2bf(v[8 + e]); }
    *(short8v*)(Bl + px_s * 72 + c_s) = h0;
    *(short8v*)(Bl + px_s * 72 + c_s + 8) = h1;
    __syncthreads();  // Bl (and, first pass, Al) visible
#pragma unroll
    for (int ks = 0; ks < 64; ks += 32) {
      const int cblk = (c0 + ks) >> 5;
      short8v bfr = *(const short8v*)(Bl + (wave * 16 + l15) * 72 + ks + lh * 8);
#pragma unroll
      for (int m = 0; m < 4; ++m) {
        short8v a = *(const short8v*)(Al + (cblk * 4 + lh) * 520 +
                                      (m * 16 + l15) * 8);
        acc[m] = __builtin_amdgcn_mfma_f32_16x16x32_bf16(a, bfr, acc[m], 0, 0, 0);
      }
    }
  }

  // epilogue: +bias, cvt bf16, store [b][y][x][c]
  const int px = wave * 16 + l15;
  short* gb = guide + ((size_t)((b * HH + y) * WW + x0 + px)) * CC;
#pragma unroll
  for (int m = 0; m < 4; ++m) {
    short4v o;
#pragma unroll
    for (int r = 0; r < 4; ++r) {
      int c = m * 16 + lh * 4 + r;
      o[r] = f2bf(acc[m][r] + bc[c]);
    }
    *(short4v*)(gb + m * 16 + lh * 4) = o;
  }
}

// ============ K2: conv3x3 + bias + softmax via MFMA (standalone) ========
// maskf[b][Y][X][28] f32 = softmax_kk(conv(guide, web) + be)
// grid 1024 = 4 b x 16x16 tiles of 8x8 px. block 256 (4 waves). LDS 14.4 KB.
__global__ __launch_bounds__(256) void k_conv(
    const short* __restrict__ guide, const short* __restrict__ web,
    const float* __restrict__ be, float* __restrict__ maskf) {
  __shared__ short Gl[10 * 10 * 72];  // [y'][x'][c], stride 72
  const int tid = threadIdx.x;
  const int bx = blockIdx.x;
  const int b = bx >> 8;
  const int t = bx & 255;
  const int y0 = (t >> 4) << 3, x0 = (t & 15) << 3;
  const int wave = tid >> 6, l = tid & 63;
  const int l15 = l & 15, lh = l >> 4;

  // ---- stage guide halo tile (zero-pad) ----
  for (int idx = tid; idx < 10 * 10 * 8; idx += 256) {
    int yp = idx / 80;
    int rem = idx - yp * 80;
    int xp = rem >> 3, cq = (rem & 7) << 3;
    int gy = y0 - 1 + yp, gx = x0 - 1 + xp;
    short8v v = {0, 0, 0, 0, 0, 0, 0, 0};
    if (gy >= 0 && gy < HH && gx >= 0 && gx < WW)
      v = *(const short8v*)(guide + ((size_t)((b * HH + gy) * WW + gx)) * CC + cq);
    *(short8v*)(Gl + (yp * 10 + xp) * 72 + cq) = v;
  }
  __syncthreads();

  // ---- conv MFMA: px = wave*16 + l15 -> (row, col) in 8x8 tile ----
  const int r_ = wave * 2 + (l15 >> 3);  // tile row 0..7
  const int cx = l15 & 7;                // tile col 0..7
  f32x4 acc0 = {0.f, 0.f, 0.f, 0.f}, acc1 = {0.f, 0.f, 0.f, 0.f};
#pragma unroll
  for (int tap = 0; tap < 9; ++tap) {
    const int dy = tap / 3, dx = tap - dy * 3;
#pragma unroll
    for (int ks = 0; ks < 64; ks += 32) {
      short8v a0 = *(const short8v*)(web + (tap * 32 + l15) * 64 + ks + lh * 8);
      short8v a1 =
          *(const short8v*)(web + (tap * 32 + 16 + l15) * 64 + ks + lh * 8);
      short8v bf = *(const short8v*)(Gl + ((r_ + dy) * 10 + cx + dx) * 72 +
                                     ks + lh * 8);
      acc0 = __builtin_amdgcn_mfma_f32_16x16x32_bf16(a0, bf, acc0, 0, 0, 0);
      acc1 = __builtin_amdgcn_mfma_f32_16x16x32_bf16(a1, bf, acc1, 0, 0, 0);
    }
  }

  // ---- bias + softmax over kk (25 vals in 4 lanes: xor 16,32) ----
  float sv[8];
#pragma unroll
  for (int r = 0; r < 4; ++r) {
    int kk0 = lh * 4 + r;            // 0..15, always < 25
    sv[r] = acc0[r] + be[kk0];
    int kk1 = 16 + lh * 4 + r;       // 16..31
    sv[4 + r] = (kk1 < KK) ? (acc1[r] + be[kk1]) : -1e30f;
  }
  float mx = sv[0];
#pragma unroll
  for (int i = 1; i < 8; ++i) mx = fmaxf(mx, sv[i]);
  mx = fmaxf(mx, __shfl_xor(mx, 16));
  mx = fmaxf(mx, __shfl_xor(mx, 32));
  float s = 0.f;
#pragma unroll
  for (int i = 0; i < 8; ++i) {
    sv[i] = __expf(sv[i] - mx);
    s += sv[i];
  }
  s += __shfl_xor(s, 16);
  s += __shfl_xor(s, 32);
  float inv = 1.f / s;

  // store: maskf[b][Y][X][28], two f32x4 per thread (second guarded)
  const int pxm = wave * 16 + l15;  // == r_*8 + cx
  const int Y = y0 + r_, X = x0 + cx;
  float* row = maskf + ((size_t)((b * HH + Y) * WW + X)) * 28;
  f32x4 o0 = {sv[0] * inv, sv[1] * inv, sv[2] * inv, sv[3] * inv};
  *(f32x4*)(row + lh * 4) = o0;
  if (lh < 3) {  // kk1 base 16,20,24 (lh==2 writes kk 24 + pad 25..27)
    f32x4 o1 = {sv[4] * inv, sv[5] * inv, sv[6] * inv, sv[7] * inv};
    *(f32x4*)(row + 16 + lh * 4) = o1;
  }
  (void)pxm;
}

// ================= K3: CARAFE upsample, channel-split ===================
// grid 2048 = 4 b x 256 tiles (8x8 hi-px) x 2 ch-halves (40 ch).
// block 256 = 8 groups (5 ch) x 32 px-pairs. Pl [cell 64][50] f32 (12.8 KB):
// channel slot g*6+cc (even base -> aligned f32x2). Masks global->regs.
__global__ __launch_bounds__(256) void k_carafe3(
    const float* __restrict__ pred, const float* __restrict__ maskf,
    float* __restrict__ out) {
  __shared__ float Pl[64 * 50];
  const int tid = threadIdx.x;
  const int bx = blockIdx.x;
  const int half = bx & 1;
  const int t = (bx >> 1) & 255;
  const int b = bx >> 9;
  const int y0 = (t >> 4) << 3, x0 = (t & 15) << 3;

  // ---- stage Pl: 40 ch x 8x8 lo cells, reflect-padded ----
  const int ylo = (y0 >> 1) - 2, xlo = (x0 >> 1) - 2;
#pragma unroll
  for (int it = 0; it < 10; ++it) {
    int idx = it * 256 + tid;          // 0..2559
    int c = idx >> 6;                  // 0..39
    int cell = idx & 63;
    int r = cell >> 3, cl = cell & 7;
    int ry = ylo + r;
    ry = ry < 0 ? -ry : (ry > 63 ? 126 - ry : ry);
    int rx = xlo + cl;
    rx = rx < 0 ? -rx : (rx > 63 ? 126 - rx : rx);
    int gg = c / 5, cc = c - gg * 5;
    Pl[cell * 50 + gg * 6 + cc] =
        pred[(((size_t)(b * CP + half * 40 + c)) << 12) + (ry << 6) + rx];
  }

  // ---- pair masks -> registers (global, L2-hot) ----
  const int g = tid >> 5;              // 0..7 -> 5-ch group
  const int pr = tid & 31;             // pry(0..7) x prx(0..3)
  const int pry = pr >> 2, prx = pr & 3;
  const int Y = y0 + pry, X = x0 + prx * 2;
  float m[2][KK];
#pragma unroll
  for (int dx = 0; dx < 2; ++dx) {
    const f32x4* mp =
        (const f32x4*)(maskf + ((size_t)((b * HH + Y) * WW + X + dx)) * 28);
#pragma unroll
    for (int v4 = 0; v4 < 7; ++v4) {
      f32x4 mv = mp[v4];
#pragma unroll
      for (int e = 0; e < 4; ++e) {
        int kk = v4 * 4 + e;
        if (kk < KK) m[dx][kk] = mv[e];
      }
    }
  }
  __syncthreads();  // Pl ready

  // ---- carafe: 5 ch x 2 px per thread ----
  float acc[5][2];
#pragma unroll
  for (int cc = 0; cc < 5; ++cc) { acc[cc][0] = 0.f; acc[cc][1] = 0.f; }

  const float* Pbase = Pl + ((pry >> 1) * 8 + prx) * 50 + g * 6;
#pragma unroll
  for (int i = 0; i < 5; ++i)
#pragma unroll
    for (int j = 0; j < 5; ++j) {
      const float* P = Pbase + (i * 8 + j) * 50;
      f32x2 p01 = *(const f32x2*)(P);
      f32x2 p23 = *(const f32x2*)(P + 2);
      float p4 = P[4];
      float m0 = m[0][i * 5 + j], m1 = m[1][i * 5 + j];
      acc[0][0] += p01.x * m0; acc[0][1] += p01.x * m1;
      acc[1][0] += p01.y * m0; acc[1][1] += p01.y * m1;
      acc[2][0] += p23.x * m0; acc[2][1] += p23.x * m1;
      acc[3][0] += p23.y * m0; acc[3][1] += p23.y * m1;
      acc[4][0] += p4    * m0; acc[4][1] += p4    * m1;
    }

#pragma unroll
  for (int cc = 0; cc < 5; ++cc) {
    float* ob = out + (((size_t)(b * CP + half * 40 + g * 5 + cc)) << 14) +
                Y * WW + X;
    f32x2 v2 = {acc[cc][0], acc[cc][1]};
    *(f32x2*)ob = v2;
  }
}

extern "C" void kernel_launch(void* const* d_in, const int* in_sizes, int n_in,
                              void* d_out, int out_size, void* d_ws,
                              size_t ws_size, hipStream_t stream) {
  (void)in_sizes; (void)n_in; (void)out_size; (void)ws_size;
  const float* pred = (const float*)d_in[0];  // (4,80,64,64)
  const float* feat = (const float*)d_in[1];  // (4,256,128,128)
  const float* wc   = (const float*)d_in[2];  // (64,256)
  const float* bc   = (const float*)d_in[3];  // (64)
  const float* we   = (const float*)d_in[4];  // (25,64,3,3)
  const float* be   = (const float*)d_in[5];  // (25)
  float* out = (float*)d_out;                 // (4,80,128,128)

  char* ws = (char*)d_ws;
  short* guide = (short*)ws;                    // 8,388,608 B bf16 [b][y][x][c]
  short* web   = (short*)(ws + 8388608);        // 36,864 B bf16 [tap][kk32][c]
  float* maskf = (float*)(ws + 8388608 + 36864);// 7,340,032 B f32 [b][Y][X][28]

  hipLaunchKernelGGL(k_compress, dim3(1024), dim3(256), 0, stream,
                     feat, wc, bc, we, guide, web);
  hipLaunchKernelGGL(k_conv, dim3(1024), dim3(256), 0, stream,
                     guide, web, be, maskf);
  hipLaunchKernelGGL(k_carafe3, dim3(2048), dim3(256), 0, stream,
                     pred, maskf, out);
}